// Round 1
// baseline (83049.261 us; speedup 1.0000x reference)
//
#include <hip/hip_runtime.h>
#include <hip/hip_bf16.h>

#define SEQ 1024
#define HID 2048
#define BAT 128
#define VOC 256

// ---------------------------------------------------------------------------
// init: copy h0 into ping-pong buffer 0
// ---------------------------------------------------------------------------
__global__ void init_h(const float* __restrict__ h0, float* __restrict__ dst) {
    int i = blockIdx.x * blockDim.x + threadIdx.x;
    for (int k = i; k < BAT * HID; k += gridDim.x * blockDim.x) dst[k] = h0[k];
}

// ---------------------------------------------------------------------------
// one RNN step: computes h_t (cols 0..2047) and y_{t-1} (cols 2048..2303)
// Both read only h_{t-1} -> no intra-kernel dependency.
// grid = (72, 4): blockIdx.x = col-group (64 for W_hh + 8 for W_lin),
//                 blockIdx.y = 32-row group. block = 256 threads.
// tile: BM=32 x BN=32, K-chunks of 128, 2x2 micro-tile per thread.
// ---------------------------------------------------------------------------
constexpr int BM = 32;
constexpr int BN = 32;
constexpr int KC = 128;

__global__ __launch_bounds__(256) void rnn_step(
    const float* __restrict__ hprev, float* __restrict__ hnext,
    const float* __restrict__ Whh,  const float* __restrict__ Wlin,
    const float* __restrict__ Wxh,  const float* __restrict__ bh,
    const float* __restrict__ blin, const int* __restrict__ x,
    float* __restrict__ out, int t)
{
    const int  cg   = blockIdx.x;          // 0..71
    const bool is_y = (cg >= 64);
    if (is_y && t == 0) return;            // y_{-1} doesn't exist (block-uniform)

    __shared__ float Asm[KC][BM + 2];      // [k][row]  (pad 34: even -> b64-aligned, conflict-free)
    __shared__ float Bsm[KC][BN + 2];      // [k][col]

    const int tid     = threadIdx.x;
    const int rowbase = blockIdx.y * BM;
    const float* Wsrc = is_y ? Wlin : Whh;
    const int    ld   = is_y ? VOC  : HID;
    const int    coff = is_y ? (cg - 64) * BN : cg * BN;

    // compute coords: 2 rows x 2 cols per thread
    const int m = (tid & 15) << 1;         // local row pair
    const int q = (tid >> 4) << 1;         // local col pair

    // staging coords
    const int ar = tid >> 3;               // 0..31  (row for A stage)
    const int ak = (tid & 7) << 4;         // 0..112 (k offset, 16 floats)
    const int bk = tid >> 1;               // 0..127 (k row for B stage)
    const int bc = (tid & 1) << 4;         // 0 or 16

    float acc00 = 0.f, acc01 = 0.f, acc10 = 0.f, acc11 = 0.f;

    for (int kb = 0; kb < HID; kb += KC) {
        // ---- stage A: h_{t-1}[32 rows][128 k] -> LDS transposed [k][row]
        const float4* ga = reinterpret_cast<const float4*>(
            &hprev[(size_t)(rowbase + ar) * HID + kb + ak]);
        #pragma unroll
        for (int i = 0; i < 4; ++i) {
            float4 v4 = ga[i];
            Asm[ak + i * 4 + 0][ar] = v4.x;
            Asm[ak + i * 4 + 1][ar] = v4.y;
            Asm[ak + i * 4 + 2][ar] = v4.z;
            Asm[ak + i * 4 + 3][ar] = v4.w;
        }
        // ---- stage B: W[128 k][32 cols] -> LDS [k][col]
        const float4* gb = reinterpret_cast<const float4*>(
            &Wsrc[(size_t)(kb + bk) * ld + coff + bc]);
        #pragma unroll
        for (int i = 0; i < 4; ++i) {
            float4 v4 = gb[i];
            *reinterpret_cast<float2*>(&Bsm[bk][bc + i * 4 + 0]) = make_float2(v4.x, v4.y);
            *reinterpret_cast<float2*>(&Bsm[bk][bc + i * 4 + 2]) = make_float2(v4.z, v4.w);
        }
        __syncthreads();

        #pragma unroll 8
        for (int kk = 0; kk < KC; ++kk) {
            float2 a = *reinterpret_cast<const float2*>(&Asm[kk][m]);
            float2 b = *reinterpret_cast<const float2*>(&Bsm[kk][q]);
            acc00 = fmaf(a.x, b.x, acc00);
            acc01 = fmaf(a.x, b.y, acc01);
            acc10 = fmaf(a.y, b.x, acc10);
            acc11 = fmaf(a.y, b.y, acc11);
        }
        __syncthreads();
    }

    const int r0 = rowbase + m;
    const int r1 = r0 + 1;
    if (!is_y) {
        // h_t = tanh(emb + h@W_hh + b_h)
        const int c0 = coff + q;
        const int xv0 = x[(size_t)r0 * SEQ + t];
        const int xv1 = x[(size_t)r1 * SEQ + t];
        const float bh0 = bh[c0], bh1 = bh[c0 + 1];
        hnext[(size_t)r0 * HID + c0]     = tanhf(acc00 + Wxh[(size_t)xv0 * HID + c0]     + bh0);
        hnext[(size_t)r0 * HID + c0 + 1] = tanhf(acc01 + Wxh[(size_t)xv0 * HID + c0 + 1] + bh1);
        hnext[(size_t)r1 * HID + c0]     = tanhf(acc10 + Wxh[(size_t)xv1 * HID + c0]     + bh0);
        hnext[(size_t)r1 * HID + c0 + 1] = tanhf(acc11 + Wxh[(size_t)xv1 * HID + c0 + 1] + bh1);
    } else {
        // y_{t-1} = h_{t-1}@W_lin + b_lin
        const int v0 = coff + q;
        const float bl0 = blin[v0], bl1 = blin[v0 + 1];
        const size_t o0 = ((size_t)r0 * SEQ + (t - 1)) * VOC + v0;
        const size_t o1 = ((size_t)r1 * SEQ + (t - 1)) * VOC + v0;
        out[o0]     = acc00 + bl0;
        out[o0 + 1] = acc01 + bl1;
        out[o1]     = acc10 + bl0;
        out[o1 + 1] = acc11 + bl1;
    }
}

// ---------------------------------------------------------------------------
// epilogue: y_1023 = h_1023 @ W_lin + b_lin, and h_last copy.
// one block per batch row; h_1023 lives in hbuf[0] (1024 steps -> even buffer).
// ---------------------------------------------------------------------------
__global__ __launch_bounds__(256) void finalize(
    const float* __restrict__ hlast, const float* __restrict__ Wlin,
    const float* __restrict__ blin, float* __restrict__ out)
{
    const int b = blockIdx.x;
    const int v = threadIdx.x;                 // 0..255
    __shared__ float hs[HID];
    for (int j = v; j < HID; j += 256) hs[j] = hlast[(size_t)b * HID + j];
    __syncthreads();

    float a0 = 0.f, a1 = 0.f, a2 = 0.f, a3 = 0.f;
    #pragma unroll 4
    for (int j = 0; j < HID; j += 4) {
        a0 = fmaf(hs[j + 0], Wlin[(size_t)(j + 0) * VOC + v], a0);
        a1 = fmaf(hs[j + 1], Wlin[(size_t)(j + 1) * VOC + v], a1);
        a2 = fmaf(hs[j + 2], Wlin[(size_t)(j + 2) * VOC + v], a2);
        a3 = fmaf(hs[j + 3], Wlin[(size_t)(j + 3) * VOC + v], a3);
    }
    out[((size_t)b * SEQ + (SEQ - 1)) * VOC + v] = (a0 + a1) + (a2 + a3) + blin[v];

    float* oh = out + (size_t)BAT * SEQ * VOC;
    for (int j = v; j < HID; j += 256) oh[(size_t)b * HID + j] = hs[j];
}

// ---------------------------------------------------------------------------
extern "C" void kernel_launch(void* const* d_in, const int* in_sizes, int n_in,
                              void* d_out, int out_size, void* d_ws, size_t ws_size,
                              hipStream_t stream) {
    const int*   x    = (const int*)  d_in[0];
    const float* h0   = (const float*)d_in[1];
    const float* Wxh  = (const float*)d_in[2];
    const float* Whh  = (const float*)d_in[3];
    const float* bh   = (const float*)d_in[4];
    const float* Wlin = (const float*)d_in[5];
    const float* blin = (const float*)d_in[6];
    float* out  = (float*)d_out;
    float* hbuf = (float*)d_ws;                      // 2 x (128*2048) f32 ping-pong
    const size_t HB = (size_t)BAT * HID;

    init_h<<<dim3(256), 256, 0, stream>>>(h0, hbuf);

    dim3 grid(72, 4);   // 64 W_hh col-groups + 8 W_lin col-groups, 4 row-groups
    for (int t = 0; t < SEQ; ++t) {
        const float* hp = hbuf + (size_t)(t & 1) * HB;
        float*       hn = hbuf + (size_t)((t + 1) & 1) * HB;
        rnn_step<<<grid, 256, 0, stream>>>(hp, hn, Whh, Wlin, Wxh, bh, blin, x, out, t);
    }
    // after 1024 steps, h_1023 is in buffer 0
    finalize<<<dim3(BAT), 256, 0, stream>>>(hbuf, Wlin, blin, out);
}

// Round 2
// 58259.045 us; speedup vs baseline: 1.4255x; 1.4255x over previous
//
#include <hip/hip_runtime.h>
#include <hip/hip_bf16.h>

#define SEQ 1024
#define HID 2048
#define BAT 128
#define VOC 256
#define NTOT 2304          // HID + VOC columns, concatenated
#define BN 48              // cols per block
#define NG 48              // col groups (2304/48)
#define BM 32              // rows per block
#define MG 4               // row groups (128/32)
#define KC 128             // K chunk
#define NCHUNK (HID / KC)  // 16
#define APAD 136           // KC + 8 shorts: 272B row stride -> 2-way-max bank alias (free)

typedef __attribute__((ext_vector_type(8))) short short8;
typedef __attribute__((ext_vector_type(4))) float f32x4;

// --- bf16 split helpers (self-contained, RN-even) ---------------------------
__device__ __forceinline__ unsigned short f2bf_rn(float v) {
    unsigned u = __float_as_uint(v);
    u += 0x7fffu + ((u >> 16) & 1u);
    return (unsigned short)(u >> 16);
}
__device__ __forceinline__ float bf2f(unsigned short s) {
    return __uint_as_float(((unsigned)s) << 16);
}

// ---------------------------------------------------------------------------
// prologue: build Wg[ng][96][2048] bf16 — rows 0..47 = hi of cols ng*48..+47,
// rows 48..95 = lo. Source: W_hh (k-major 2048x2048) cols 0..2047, W_lin
// (2048x256) cols 2048..2303. One-time strided reads, ~10 us.
// ---------------------------------------------------------------------------
__global__ __launch_bounds__(256) void wsplit(
    const float* __restrict__ Whh, const float* __restrict__ Wlin,
    short* __restrict__ Wg)
{
    const int n  = blockIdx.x;          // 0..2303
    const int ng = n / BN, rl = n % BN;
    short* dhi = Wg + ((size_t)ng * 96 + rl) * HID;
    short* dlo = dhi + (size_t)BN * HID;
    for (int k = threadIdx.x; k < HID; k += 256) {
        float v = (n < HID) ? Whh[(size_t)k * HID + n]
                            : Wlin[(size_t)k * VOC + (n - HID)];
        unsigned short h = f2bf_rn(v);
        dhi[k] = (short)h;
        dlo[k] = (short)f2bf_rn(v - bf2f(h));
    }
}

// ---------------------------------------------------------------------------
// init: split h0 into group-major hi/lo layout: hb[g][rl][k] hi, hb[g][rl+32][k] lo
// ---------------------------------------------------------------------------
__global__ __launch_bounds__(256) void hsplit(
    const float* __restrict__ h0, short* __restrict__ hb)
{
    for (int i = blockIdx.x * 256 + threadIdx.x; i < BAT * HID;
         i += gridDim.x * 256) {
        int row = i / HID, k = i % HID;
        int g = row >> 5, rl = row & 31;
        float v = h0[i];
        unsigned short h = f2bf_rn(v);
        short* base = hb + (size_t)g * 64 * HID;
        base[(size_t)rl * HID + k]        = (short)h;
        base[(size_t)(rl + 32) * HID + k] = (short)f2bf_rn(v - bf2f(h));
    }
}

// ---------------------------------------------------------------------------
// one step: C[32x48] = hprev[32x2048] @ Wcat[2048x48] via split-bf16 3-product
// MFMA 16x16x32. Cols<2048: h_t = tanh(C+emb+bh) -> split store. Cols>=2048:
// y_{t-1} = C + blin. 6 waves = 2x3 16x16 subtiles. 2-deep register prefetch
// pipeline (static indexing) to hit the ~140 GB/s per-CU L2 BW floor.
// ---------------------------------------------------------------------------
__global__ __launch_bounds__(384) void rnn_step(
    const short* __restrict__ hprev, short* __restrict__ hnext,
    const short* __restrict__ Wg,   const float* __restrict__ Wxh,
    const float* __restrict__ bh,   const float* __restrict__ blin,
    const int* __restrict__ x,      float* __restrict__ out, int t)
{
    __shared__ short Alds[64 * APAD];   // rows 0..31 hi, 32..63 lo
    __shared__ short Wlds[96 * APAD];   // rows 0..47 hi, 48..95 lo

    const int tid = threadIdx.x;
    const int ng  = blockIdx.x;         // 0..47  (col group; %8 spreads W over XCDs)
    const int mg  = blockIdx.y;         // 0..3   (row group)
    const short* Ag  = hprev + (size_t)mg * 64 * HID;
    const short* Wgb = Wg    + (size_t)ng * 96 * HID;

    uint4 a0[3], w0[4], a1[3], w1[4];   // named double buffers (rule #20: static idx)

    auto loadA = [&](int c, uint4* a) {
        const int kb = c * KC;
        #pragma unroll
        for (int j = 0; j < 3; ++j) {
            int i = tid + j * 384;
            if (i < 1024) {
                int row = i >> 4, ko = (i & 15) * 8;
                a[j] = *reinterpret_cast<const uint4*>(&Ag[(size_t)row * HID + kb + ko]);
            }
        }
    };
    auto loadW = [&](int c, uint4* w) {
        const int kb = c * KC;
        #pragma unroll
        for (int j = 0; j < 4; ++j) {
            int i = tid + j * 384;
            int row = i >> 4, ko = (i & 15) * 8;
            w[j] = *reinterpret_cast<const uint4*>(&Wgb[(size_t)row * HID + kb + ko]);
        }
    };
    auto storeA = [&](uint4* a) {
        #pragma unroll
        for (int j = 0; j < 3; ++j) {
            int i = tid + j * 384;
            if (i < 1024) {
                int row = i >> 4, ko = (i & 15) * 8;
                *reinterpret_cast<uint4*>(&Alds[row * APAD + ko]) = a[j];
            }
        }
    };
    auto storeW = [&](uint4* w) {
        #pragma unroll
        for (int j = 0; j < 4; ++j) {
            int i = tid + j * 384;
            int row = i >> 4, ko = (i & 15) * 8;
            *reinterpret_cast<uint4*>(&Wlds[row * APAD + ko]) = w[j];
        }
    };

    const int lane = tid & 63;
    const int wv   = tid >> 6;          // 0..5
    const int mi   = wv & 1;            // 16-row subtile
    const int ni   = wv >> 1;           // 16-col subtile (0..2)
    const int l15  = lane & 15;
    const int kl   = (lane >> 4) * 8;

    f32x4 acc = {0.f, 0.f, 0.f, 0.f};
    const short* Abase = &Alds[(mi * 16 + l15) * APAD + kl];
    const short* Bbase = &Wlds[(ni * 16 + l15) * APAD + kl];

    auto mfma_chunk = [&]() {
        #pragma unroll
        for (int kk = 0; kk < 4; ++kk) {
            short8 ah = *reinterpret_cast<const short8*>(&Abase[kk * 32]);
            short8 al = *reinterpret_cast<const short8*>(&Abase[32 * APAD + kk * 32]);
            short8 bh = *reinterpret_cast<const short8*>(&Bbase[kk * 32]);
            short8 bl = *reinterpret_cast<const short8*>(&Bbase[48 * APAD + kk * 32]);
            acc = __builtin_amdgcn_mfma_f32_16x16x32_bf16(ah, bh, acc, 0, 0, 0);
            acc = __builtin_amdgcn_mfma_f32_16x16x32_bf16(ah, bl, acc, 0, 0, 0);
            acc = __builtin_amdgcn_mfma_f32_16x16x32_bf16(al, bh, acc, 0, 0, 0);
        }
    };

    loadA(0, a0); loadW(0, w0);
    loadA(1, a1); loadW(1, w1);

    for (int c = 0; c < NCHUNK; c += 2) {
        __syncthreads();
        storeA(a0); storeW(w0);
        __syncthreads();
        if (c + 2 < NCHUNK) { loadA(c + 2, a0); loadW(c + 2, w0); }
        mfma_chunk();

        __syncthreads();
        storeA(a1); storeW(w1);
        __syncthreads();
        if (c + 3 < NCHUNK) { loadA(c + 3, a1); loadW(c + 3, w1); }
        mfma_chunk();
    }

    // ---- epilogue: C/D layout col = lane&15, row = (lane>>4)*4 + r  [m89]
    const int col = ng * BN + ni * 16 + l15;      // 0..2303
    const int rl0 = mi * 16 + (lane >> 4) * 4;    // local row 0..31

    if (col < HID) {
        short* hn = hnext + (size_t)mg * 64 * HID;
        #pragma unroll
        for (int r = 0; r < 4; ++r) {
            const int rl   = rl0 + r;
            const int grow = mg * 32 + rl;
            const int xv   = x[(size_t)grow * SEQ + t];
            float v  = acc[r] + Wxh[(size_t)xv * HID + col] + bh[col];
            float th = tanhf(v);
            unsigned short hi = f2bf_rn(th);
            hn[(size_t)rl * HID + col]        = (short)hi;
            hn[(size_t)(rl + 32) * HID + col] = (short)f2bf_rn(th - bf2f(hi));
            if (t == SEQ - 1)
                out[(size_t)BAT * SEQ * VOC + (size_t)grow * HID + col] = th;
        }
    } else if (t > 0) {
        const int vc = col - HID;
        const float bl = blin[vc];
        #pragma unroll
        for (int r = 0; r < 4; ++r) {
            const int grow = mg * 32 + rl0 + r;
            out[((size_t)grow * SEQ + (t - 1)) * VOC + vc] = acc[r] + bl;
        }
    }
}

// ---------------------------------------------------------------------------
// epilogue kernel: y_1023 = h_1023 @ W_lin + b_lin (h_last fp32 already
// written by step t=1023). One block per batch row; one-time ~10 us.
// ---------------------------------------------------------------------------
__global__ __launch_bounds__(256) void finalize(
    const short* __restrict__ hb, const float* __restrict__ Wlin,
    const float* __restrict__ blin, float* __restrict__ out)
{
    const int b = blockIdx.x, v = threadIdx.x;
    __shared__ float hs[HID];
    const int g = b >> 5, rl = b & 31;
    const short* hi = hb + (size_t)g * 64 * HID + (size_t)rl * HID;
    const short* lo = hi + (size_t)32 * HID;
    for (int j = v; j < HID; j += 256)
        hs[j] = bf2f((unsigned short)hi[j]) + bf2f((unsigned short)lo[j]);
    __syncthreads();

    float a0 = 0.f, a1 = 0.f, a2 = 0.f, a3 = 0.f;
    #pragma unroll 4
    for (int j = 0; j < HID; j += 4) {
        a0 = fmaf(hs[j + 0], Wlin[(size_t)(j + 0) * VOC + v], a0);
        a1 = fmaf(hs[j + 1], Wlin[(size_t)(j + 1) * VOC + v], a1);
        a2 = fmaf(hs[j + 2], Wlin[(size_t)(j + 2) * VOC + v], a2);
        a3 = fmaf(hs[j + 3], Wlin[(size_t)(j + 3) * VOC + v], a3);
    }
    out[((size_t)b * SEQ + SEQ - 1) * VOC + v] = (a0 + a1) + (a2 + a3) + blin[v];
}

// ---------------------------------------------------------------------------
extern "C" void kernel_launch(void* const* d_in, const int* in_sizes, int n_in,
                              void* d_out, int out_size, void* d_ws, size_t ws_size,
                              hipStream_t stream) {
    const int*   x    = (const int*)  d_in[0];
    const float* h0   = (const float*)d_in[1];
    const float* Wxh  = (const float*)d_in[2];
    const float* Whh  = (const float*)d_in[3];
    const float* bh   = (const float*)d_in[4];
    const float* Wlin = (const float*)d_in[5];
    const float* blin = (const float*)d_in[6];
    float* out = (float*)d_out;

    // workspace layout (shorts): Wg[48*96*2048] | hbuf0[4*64*2048] | hbuf1[...]
    short* Wg  = (short*)d_ws;
    short* hb0 = Wg  + (size_t)NG * 96 * HID;
    short* hb1 = hb0 + (size_t)MG * 64 * HID;

    wsplit<<<dim3(NTOT), 256, 0, stream>>>(Whh, Wlin, Wg);
    hsplit<<<dim3(256), 256, 0, stream>>>(h0, hb0);

    dim3 grid(NG, MG);   // (48, 4)
    for (int t = 0; t < SEQ; ++t) {
        short* hp = (t & 1) ? hb1 : hb0;
        short* hn = (t & 1) ? hb0 : hb1;
        rnn_step<<<grid, 384, 0, stream>>>(hp, hn, Wg, Wxh, bh, blin, x, out, t);
    }
    // h_1023 sits in hb0 (even parity after 1024 steps)
    finalize<<<dim3(BAT), 256, 0, stream>>>(hb0, Wlin, blin, out);
}